// Round 3
// baseline (159.270 us; speedup 1.0000x reference)
//
#include <hip/hip_runtime.h>
#include <math.h>

// ---------------------------------------------------------------------------
// Mann eddy-lifetime: tau = gamma * t^{-2/3} / sqrt(2F1(1/3,17/6,4/3,-t^-2))
// with t = L*||k||. Via Pfaff transform, 2F1 = (t^2 w)^{1/3} * s(w),
// w = 1/(1+t^2), s(w) = sum C_n w^n. Algebra collapses the output to
//   tau = rsqrt( t^2 * cbrt(w) * s(w) )
// NT=48 series terms: truncation ~8e-6 rel., far inside absmax threshold.
//
// Round-3 structure: persistent blocks + double-buffered LDS prefetch.
//  Evidence: R0 (48-B chunk loads) and R2 (coalesced LDS staging) both
//  land at ~35-37 us vs a ~21 us BW floor -> spatial pattern is not the
//  limiter; the load->barrier->compute->exit phase structure is (memory
//  pipe idle during compute, low issue duty cycle).
//  - grid = 2048 persistent blocks, 4 tiles each (tile = 1024 pts = 12 KB).
//  - Per iteration: barrier; async global_load_lds (width 16) of tile t+1
//    into the other buffer; compute tile t. Prefetch has the whole compute
//    phase (~500-900 cyc) to land before the next barrier drains vmcnt.
//  - LDS reads: thread t handles points {t, t+256j}; scalar reads at
//    float offset 3p+c -> bank (3t+c)%32, 2-way aliasing = free (vs the
//    8-way conflict of R2's stride-12 b128 reads).
//  - 24 KB LDS/block -> 6 blocks/CU resident; 6x12 KB loads in flight/CU.
//  - Math: NT=48 Horner, v_rcp_f32, raw v_log/v_exp/v_rsq builtins.
//  - Store: coalesced dword/lane, nontemporal (write-only stream).
// ---------------------------------------------------------------------------

typedef float f4 __attribute__((ext_vector_type(4)));

typedef const __attribute__((address_space(1))) void* gas_ptr;
typedef __attribute__((address_space(3))) void* las_ptr;

constexpr int NT       = 48;
constexpr int TILE_PTS = 1024;          // points per tile
constexpr int TILE_F4  = 768;           // 12 KB per tile

struct CoefArr { float v[NT]; };

constexpr CoefArr gen_coefs() {
    CoefArr r{};
    double term = 1.0;
    r.v[0] = 1.0f;
    for (int n = 0; n + 1 < NT; ++n) {
        const double a  = 1.0 / 3.0;
        const double bp = -1.5;        // c - b = 4/3 - 17/6
        const double c  = 4.0 / 3.0;
        term *= ((a + n) * (bp + n)) / ((c + n) * (n + 1.0));
        r.v[n + 1] = (float)term;
    }
    return r;
}

constexpr CoefArr COEF = gen_coefs();   // folded to immediates at compile time

__device__ __forceinline__ float mann_tau(float t2) {
    // w in (0,1]; t2 == 0 handled by caller (masked to 0)
    float w = __builtin_amdgcn_rcpf(1.0f + t2);   // v_rcp_f32, ~1 ulp
    float s = COEF.v[NT - 1];
#pragma unroll
    for (int n = NT - 2; n >= 0; --n) s = fmaf(s, w, COEF.v[n]);
    // cbrt(w) via hw log2/exp2 (w > 0 always)
    float cw = __builtin_amdgcn_exp2f(__builtin_amdgcn_logf(w) * (1.0f / 3.0f));
    return __builtin_amdgcn_rsqf(t2 * cw * s);    // v_rsq_f32
}

// Async global->LDS stage of one 12-KB tile; 3 x 16B per thread, linear.
__device__ __forceinline__ void stage_tile(f4* ldsDst, const f4* gSrc, int tid) {
#pragma unroll
    for (int i = 0; i < 3; ++i) {
        __builtin_amdgcn_global_load_lds(
            (gas_ptr)(gSrc + i * 256 + tid),
            (las_ptr)(ldsDst + i * 256 + tid),
            16, 0, 0);
    }
}

__global__ __launch_bounds__(256) void mann_elt_kernel(
    const float* __restrict__ k,
    const float* __restrict__ Lp,
    const float* __restrict__ gp,
    float* __restrict__ out,
    int n)               // n = number of output points
{
    const int tid    = threadIdx.x;
    const int ntiles = n / TILE_PTS;

    __shared__ f4 buf[2][TILE_F4];      // 24 KB -> 6 blocks/CU

    const float L  = Lp[0];
    const float g  = gp[0];
    const float L2 = L * L;

    const f4* kg = (const f4*)k;

    int tile = blockIdx.x;
    const int stride = gridDim.x;

    if (tile < ntiles)
        stage_tile(buf[0], kg + (size_t)tile * TILE_F4, tid);

    int cur = 0;
    for (; tile < ntiles; tile += stride) {
        __syncthreads();                 // drains vmcnt: buf[cur] ready,
                                         // and all reads of buf[cur^1] done
        const int nxt = tile + stride;
        if (nxt < ntiles)
            stage_tile(buf[cur ^ 1], kg + (size_t)nxt * TILE_F4, tid);

        const float* s = (const float*)buf[cur];
        const long outBase = (long)tile * TILE_PTS + tid;

        float x[4], y[4], z[4];
#pragma unroll
        for (int j = 0; j < 4; ++j) {
            const int p = tid + j * 256;
            x[j] = s[3 * p + 0];
            y[j] = s[3 * p + 1];
            z[j] = s[3 * p + 2];
        }

        float r[4];
#pragma unroll
        for (int j = 0; j < 4; ++j) {
            float t2  = L2 * fmaf(x[j], x[j], fmaf(y[j], y[j], z[j] * z[j]));
            float tau = mann_tau(t2);
            r[j] = (t2 > 0.0f) ? g * tau : 0.0f;
        }

#pragma unroll
        for (int j = 0; j < 4; ++j)
            __builtin_nontemporal_store(r[j], out + outBase + j * 256);

        cur ^= 1;
    }

    // remainder (n % 1024 points) — block 0, scalar fallback
    if (blockIdx.x == 0) {
        for (long i = (long)ntiles * TILE_PTS + tid; i < (long)n; i += 256) {
            float kx = k[3 * i + 0];
            float ky = k[3 * i + 1];
            float kz = k[3 * i + 2];
            float t2  = L2 * (kx * kx + ky * ky + kz * kz);
            float tau = mann_tau(t2);
            out[i] = (t2 > 0.0f) ? g * tau : 0.0f;
        }
    }
}

extern "C" void kernel_launch(void* const* d_in, const int* in_sizes, int n_in,
                              void* d_out, int out_size, void* d_ws, size_t ws_size,
                              hipStream_t stream) {
    const float* k  = (const float*)d_in[0];
    const float* L  = (const float*)d_in[1];
    const float* g  = (const float*)d_in[2];
    float* out = (float*)d_out;

    const int n      = out_size;        // 256*256*128 = 8388608 points
    const int ntiles = n / TILE_PTS;    // 8192
    int grid = ntiles < 2048 ? (ntiles > 0 ? ntiles : 1) : 2048;

    mann_elt_kernel<<<grid, 256, 0, stream>>>(k, L, g, out, n);
}

// Round 4
// 148.062 us; speedup vs baseline: 1.0757x; 1.0757x over previous
//
#include <hip/hip_runtime.h>
#include <math.h>

// ---------------------------------------------------------------------------
// Mann eddy-lifetime: tau = gamma * t^{-2/3} / sqrt(2F1(1/3,17/6,4/3,-t^-2))
// with t = L*||k||. Via Pfaff transform, 2F1 = (t^2 w)^{1/3} * s(w),
// w = 1/(1+t^2), s(w) = sum C_n w^n. Algebra collapses the output to
//   tau = rsqrt( t^2 * cbrt(w) * s(w) )
//
// Round-4: R2 structure (best: 155.2 us) + two "stop extra work" levers.
//  Evidence: R0/R2/R3 (chunked / staged / pipelined-prefetch) all ~35-39 us
//  kernel vs ~21 us traffic floor -> load schedule is not the limiter.
//  Shared suspects:
//   (a) allocating reads force-evict the harness poison fill's dirty L3
//       lines (~402 MB fill precedes us) -> hidden writeback in our window.
//       (134+~100)/6.7 TB/s ~= 35 us, matching the plateau. Fix: NT loads.
//       Safe here because each staging instruction reads a fully-used
//       contiguous 1 KiB/wave (unlike R1's chunked pattern, where NT
//       dropped partially-used lines and regressed).
//   (b) NT=48 Horner chain. Tail analysis: C_16 ~ 9.5e-6, tail ~6e-5 abs
//       -> ~4.4e-5 rel on tau after rsqrt -> ~2e-3 abs at tau_max~50.
//       NT=16 is safe (absmax 0.03125 is series-independent: R1's 64->48
//       change didn't move it).
//  - Global->LDS: 3 x float4/thread, lane-consecutive, nontemporal.
//  - LDS->reg: 3 x float4/thread, 48-B contiguous.
//  - Math: NT=16 Horner, v_rcp_f32, raw v_log/v_exp/v_rsq builtins.
//  - Store: 1 coalesced float4/thread, nontemporal.
// ---------------------------------------------------------------------------

typedef float f4 __attribute__((ext_vector_type(4)));

constexpr int NT = 16;

struct CoefArr { float v[NT]; };

constexpr CoefArr gen_coefs() {
    CoefArr r{};
    double term = 1.0;
    r.v[0] = 1.0f;
    for (int n = 0; n + 1 < NT; ++n) {
        const double a  = 1.0 / 3.0;
        const double bp = -1.5;        // c - b = 4/3 - 17/6
        const double c  = 4.0 / 3.0;
        term *= ((a + n) * (bp + n)) / ((c + n) * (n + 1.0));
        r.v[n + 1] = (float)term;
    }
    return r;
}

constexpr CoefArr COEF = gen_coefs();   // folded to immediates at compile time

__device__ __forceinline__ float mann_tau(float t2) {
    // w in (0,1]; t2 == 0 handled by caller (masked to 0)
    float w = __builtin_amdgcn_rcpf(1.0f + t2);   // v_rcp_f32, ~1 ulp
    float s = COEF.v[NT - 1];
#pragma unroll
    for (int n = NT - 2; n >= 0; --n) s = fmaf(s, w, COEF.v[n]);
    // cbrt(w) via hw log2/exp2 (w > 0 always)
    float cw = __builtin_amdgcn_exp2f(__builtin_amdgcn_logf(w) * (1.0f / 3.0f));
    return __builtin_amdgcn_rsqf(t2 * cw * s);    // v_rsq_f32
}

__global__ __launch_bounds__(256) void mann_elt_kernel(
    const float* __restrict__ k,
    const float* __restrict__ Lp,
    const float* __restrict__ gp,
    float* __restrict__ out,
    int n)               // n = number of output elements (points)
{
    const int  t        = threadIdx.x;
    const long blockPts = (long)blockIdx.x * 1024;   // points per block

    const float L  = Lp[0];
    const float g  = gp[0];
    const float L2 = L * L;

    __shared__ f4 sk4[768];                          // 12 KB

    if (blockPts + 1024 <= (long)n) {
        // ---- fast path: full block, fully coalesced nontemporal staging ----
        const f4* kg     = (const f4*)k;
        const long base4 = blockPts * 3 / 4;         // = blockIdx.x * 768
#pragma unroll
        for (int i = 0; i < 3; ++i) {
            f4 v = __builtin_nontemporal_load(&kg[base4 + t + i * 256]);
            sk4[t + i * 256] = v;
        }
        __syncthreads();

        // this thread's 4 points: floats [t*12, t*12+12) in the block tile
        const float* skf = (const float*)sk4;
        const f4*    sp  = (const f4*)(skf + t * 12); // 48-B, 16-B aligned
        f4 p0 = sp[0];
        f4 p1 = sp[1];
        f4 p2 = sp[2];

        float n2[4];
        n2[0] = fmaf(p0[0], p0[0], fmaf(p0[1], p0[1], p0[2] * p0[2]));
        n2[1] = fmaf(p0[3], p0[3], fmaf(p1[0], p1[0], p1[1] * p1[1]));
        n2[2] = fmaf(p1[2], p1[2], fmaf(p1[3], p1[3], p2[0] * p2[0]));
        n2[3] = fmaf(p2[1], p2[1], fmaf(p2[2], p2[2], p2[3] * p2[3]));

        f4 o;
#pragma unroll
        for (int j = 0; j < 4; ++j) {
            float t2  = L2 * n2[j];
            float tau = mann_tau(t2);
            o[j] = (t2 > 0.0f) ? g * tau : 0.0f;
        }
        // coalesced 16-B/lane store; write-only stream -> nontemporal
        __builtin_nontemporal_store(o, (f4*)(out + blockPts) + t);
    } else {
        // ---- tail block (n not divisible by 1024) — scalar fallback ----
        for (int j = 0; j < 4; ++j) {
            const long i = blockPts + (long)t * 4 + j;
            if (i >= (long)n) break;
            float kx = k[3 * i + 0];
            float ky = k[3 * i + 1];
            float kz = k[3 * i + 2];
            float t2  = L2 * (kx * kx + ky * ky + kz * kz);
            float tau = mann_tau(t2);
            out[i] = (t2 > 0.0f) ? g * tau : 0.0f;
        }
    }
}

extern "C" void kernel_launch(void* const* d_in, const int* in_sizes, int n_in,
                              void* d_out, int out_size, void* d_ws, size_t ws_size,
                              hipStream_t stream) {
    const float* k  = (const float*)d_in[0];
    const float* L  = (const float*)d_in[1];
    const float* g  = (const float*)d_in[2];
    float* out = (float*)d_out;

    const int n = out_size;                 // 256*256*128 = 8388608 points
    const int block = 256;
    const int ptsPerBlock = 1024;           // 4 points/thread
    const int grid = (n + ptsPerBlock - 1) / ptsPerBlock;   // 8192 exactly

    mann_elt_kernel<<<grid, block, 0, stream>>>(k, L, g, out, n);
}